// Round 6
// baseline (194.376 us; speedup 1.0000x reference)
//
#include <hip/hip_runtime.h>

// VolSDF volume rendering, latency-optimized:
//   4 rays/wave, 4 points/lane, independent 32-lane-half scans.
// - All global loads are float4 (dwordx4, 16B/lane).
// - Exclusive cumsum = per-lane sum of 4 dd's -> 5-step shfl_up scan (width 32).
// - Lane 31 of each half owns the FAR_DELTA sentinel segment; it is kept OUT
//   of the scan (f32 ulp at 1e11 is ~8192 -> catastrophic cancellation).
// - Two ray-pairs (u=0,1) per wave: loads issued up-front, two independent
//   shuffle chains interleave to cover cross-lane latency.

#define ALPHA_C       10.0f
#define INV_BETA      20.0f      // 1 / 0.05
#define FAR_DELTA     1.0e10f
#define N_PTS         128
#define RAYS_PER_WAVE 4

__device__ __forceinline__ float sdf_density(float dist) {
    float sd = -dist;
    // Laplace CDF: sd<=0 -> 0.5*exp(sd/beta); else 1 - 0.5*exp(-sd/beta)
    float e  = __expf(-fabsf(sd) * INV_BETA);
    return (sd <= 0.0f) ? (ALPHA_C * 0.5f * e)
                        : (ALPHA_C * (1.0f - 0.5f * e));
}

__global__ __launch_bounds__(256) void volsdf_render_kernel(
    const float4* __restrict__ dist4,    // 32 float4 per ray
    const float4* __restrict__ depth4,   // 32 float4 per ray
    const float4* __restrict__ col4,     // 96 float4 per ray
    float* __restrict__ out,
    int n_rays)
{
    const int wave = (int)((blockIdx.x * blockDim.x + threadIdx.x) >> 6);
    const int lane = (int)(threadIdx.x & 63);
    const int half = lane >> 5;          // which ray of the pair
    const int i    = lane & 31;          // position within the 32-lane half

    const int base_ray = wave * RAYS_PER_WAVE;
    if (base_ray >= n_rays) return;      // wave-uniform (n_rays % 4 == 0)

    // ---- issue ALL loads up front (10x dwordx4 in flight) ----
    float4 d4[2], z4[2], c0[2], c1[2], c2[2];
    #pragma unroll
    for (int u = 0; u < 2; ++u) {
        const size_t ray = (size_t)(base_ray + 2 * u + half);
        d4[u] = dist4 [ray * 32 + i];
        z4[u] = depth4[ray * 32 + i];
        const float4* c = col4 + ray * 96 + 3 * i;
        c0[u] = c[0];                    // r0 g0 b0 r1
        c1[u] = c[1];                    // g1 b1 r2 g2
        c2[u] = c[2];                    // b2 r3 g3 b3
    }

    #pragma unroll
    for (int u = 0; u < 2; ++u) {
        const int ray = base_ray + 2 * u + half;
        const float4 z = z4[u], d = d4[u];

        // deltas: 3 in-register, last needs next lane's z.x
        float zn  = __shfl_down(z.x, 1, 32);
        float dd0 = sdf_density(d.x) * (z.y - z.x);
        float dd1 = sdf_density(d.y) * (z.z - z.y);
        float dd2 = sdf_density(d.z) * (z.w - z.z);
        float dd3 = sdf_density(d.w) * ((i == 31) ? FAR_DELTA : (zn - z.w));

        // exclusive prefix over this half's 128 points (sentinel excluded)
        float s = dd0 + dd1 + dd2 + ((i == 31) ? 0.0f : dd3);
        float incl = s;
        #pragma unroll
        for (int off = 1; off < 32; off <<= 1) {
            float v = __shfl_up(incl, off, 32);
            if (i >= off) incl += v;
        }
        float excl = incl - s;           // sum of dd_j, j < 4i

        float p1 = excl + dd0;
        float p2 = p1 + dd1;
        float p3 = p2 + dd2;
        float w0 = __expf(-excl) * (1.0f - __expf(-dd0));
        float w1 = __expf(-p1)   * (1.0f - __expf(-dd1));
        float w2 = __expf(-p2)   * (1.0f - __expf(-dd2));
        float w3 = __expf(-p3)   * (1.0f - __expf(-dd3));  // i==31: exp(-1e11)=0 -> w3=T

        float r = w0 * c0[u].x + w1 * c0[u].w + w2 * c1[u].z + w3 * c2[u].y;
        float g = w0 * c0[u].y + w1 * c1[u].x + w2 * c1[u].w + w3 * c2[u].z;
        float b = w0 * c0[u].z + w1 * c1[u].y + w2 * c2[u].x + w3 * c2[u].w;

        // half-wave tree reduction (r,g,b 3-way ILP)
        #pragma unroll
        for (int off = 16; off >= 1; off >>= 1) {
            r += __shfl_down(r, off, 32);
            g += __shfl_down(g, off, 32);
            b += __shfl_down(b, off, 32);
        }
        if (i == 0) {
            float* o = out + (size_t)ray * 3;
            o[0] = r; o[1] = g; o[2] = b;
        }
    }
}

extern "C" void kernel_launch(void* const* d_in, const int* in_sizes, int n_in,
                              void* d_out, int out_size, void* d_ws, size_t ws_size,
                              hipStream_t stream) {
    const float4* dist4  = (const float4*)d_in[0];
    const float4* col4   = (const float4*)d_in[1];
    const float4* depth4 = (const float4*)d_in[2];
    float* out = (float*)d_out;

    const int n_rays = in_sizes[0] / N_PTS;              // 65536
    const int waves  = n_rays / RAYS_PER_WAVE;           // 16384
    const int threads = 256;                             // 4 waves/block
    const int blocks = (waves * 64 + threads - 1) / threads;   // 4096
    volsdf_render_kernel<<<blocks, threads, 0, stream>>>(dist4, depth4, col4, out, n_rays);
}

// Round 10
// 193.973 us; speedup vs baseline: 1.0021x; 1.0021x over previous
//
#include <hip/hip_runtime.h>

// VolSDF volume rendering.
// r6 diagnosis: line-miss-throughput-bound — 48B-stride color loads touch
// 2.2x the cache lines of an ideal stream. Fix: coalesced color staging.
// r7 post-mortem: CROSS-WAVE LDS staging deterministically diverged after the
// first launch under graph replay; non-LDS versions never did. This version
// keeps the staging but makes it WAVE-LOCAL: each wave stages and reads only
// its own 4 rays' color, so correctness does not depend on __syncthreads or
// any inter-wave ordering.
//   - 4 rays/wave, 4 points/lane, independent 32-lane-half scans.
//   - dist/depth: direct coalesced float4 loads (already minimal lines).
//   - color: per-wave coalesced global->LDS (6 x 1KB dwordx4), then
//     48B-stride LDS reads (mild 4-way bank pattern, negligible).
//   - FAR_DELTA sentinel kept OUT of the scan (f32 ulp at 1e11 ~ 8192 ->
//     catastrophic cancellation).

#define ALPHA_C         10.0f
#define INV_BETA        20.0f      // 1 / 0.05
#define FAR_DELTA       1.0e10f
#define N_PTS           128
#define WAVES_PER_BLOCK 4
#define RAYS_PER_WAVE   4
#define C4_PER_RAY      96         // 128 pts * 3 ch / 4 floats per float4
#define C4_PER_WAVE     (RAYS_PER_WAVE * C4_PER_RAY)   // 384

__device__ __forceinline__ float sdf_density(float dist) {
    float sd = -dist;
    // Laplace CDF: sd<=0 -> 0.5*exp(sd/beta); else 1 - 0.5*exp(-sd/beta)
    float e  = __expf(-fabsf(sd) * INV_BETA);
    return (sd <= 0.0f) ? (ALPHA_C * 0.5f * e)
                        : (ALPHA_C * (1.0f - 0.5f * e));
}

__global__ __launch_bounds__(256) void volsdf_render_kernel(
    const float4* __restrict__ dist4,    // 32 float4 per ray
    const float4* __restrict__ depth4,   // 32 float4 per ray
    const float4* __restrict__ col4,     // 96 float4 per ray
    float* __restrict__ out)
{
    __shared__ float4 scol[WAVES_PER_BLOCK][C4_PER_WAVE];   // 24 KB

    const int tid  = (int)threadIdx.x;
    const int wv   = tid >> 6;            // wave within block: 0..3
    const int lane = tid & 63;
    const int half = lane >> 5;           // which ray of the pair
    const int i    = lane & 31;           // position within the 32-lane half

    const int wave_ray = (int)blockIdx.x * (WAVES_PER_BLOCK * RAYS_PER_WAVE)
                       + wv * RAYS_PER_WAVE;

    // ---- color: WAVE-LOCAL coalesced global -> LDS (6 x 1KB per wave) ----
    {
        const float4* wc = col4 + (size_t)wave_ray * C4_PER_RAY;
        #pragma unroll
        for (int j = 0; j < 6; ++j) {
            scol[wv][j * 64 + lane] = wc[j * 64 + lane];
        }
    }

    // ---- dist/depth: direct coalesced float4 loads ----
    float4 d4[2], z4[2];
    #pragma unroll
    for (int u = 0; u < 2; ++u) {
        const size_t ray = (size_t)(wave_ray + 2 * u + half);
        d4[u] = dist4 [ray * 32 + i];
        z4[u] = depth4[ray * 32 + i];
    }

    __syncthreads();   // not required for correctness (wave-local), kept cheap

    #pragma unroll
    for (int u = 0; u < 2; ++u) {
        const int ray_l = 2 * u + half;           // ray within this wave
        const int ray   = wave_ray + ray_l;
        const float4 z = z4[u], d = d4[u];

        // deltas: 3 in-register, last needs next lane's z.x
        float zn  = __shfl_down(z.x, 1, 32);
        float dd0 = sdf_density(d.x) * (z.y - z.x);
        float dd1 = sdf_density(d.y) * (z.z - z.y);
        float dd2 = sdf_density(d.z) * (z.w - z.z);
        float dd3 = sdf_density(d.w) * ((i == 31) ? FAR_DELTA : (zn - z.w));

        // exclusive prefix over this half's 128 points (sentinel excluded)
        float s = dd0 + dd1 + dd2 + ((i == 31) ? 0.0f : dd3);
        float incl = s;
        #pragma unroll
        for (int off = 1; off < 32; off <<= 1) {
            float v = __shfl_up(incl, off, 32);
            if (i >= off) incl += v;
        }
        float excl = incl - s;                    // sum of dd_j, j < 4i

        float p1 = excl + dd0;
        float p2 = p1 + dd1;
        float p3 = p2 + dd2;
        float w0 = __expf(-excl) * (1.0f - __expf(-dd0));
        float w1 = __expf(-p1)   * (1.0f - __expf(-dd1));
        float w2 = __expf(-p2)   * (1.0f - __expf(-dd2));
        float w3 = __expf(-p3)   * (1.0f - __expf(-dd3));  // i==31: exp(-1e11)=0 -> w3=T

        // color from this wave's own LDS region
        const float4* c = &scol[wv][ray_l * C4_PER_RAY + 3 * i];
        const float4 ca = c[0];                   // r0 g0 b0 r1
        const float4 cb = c[1];                   // g1 b1 r2 g2
        const float4 cc = c[2];                   // b2 r3 g3 b3

        float r = w0 * ca.x + w1 * ca.w + w2 * cb.z + w3 * cc.y;
        float g = w0 * ca.y + w1 * cb.x + w2 * cb.w + w3 * cc.z;
        float b = w0 * ca.z + w1 * cb.y + w2 * cc.x + w3 * cc.w;

        // half-wave tree reduction (r,g,b 3-way ILP)
        #pragma unroll
        for (int off = 16; off >= 1; off >>= 1) {
            r += __shfl_down(r, off, 32);
            g += __shfl_down(g, off, 32);
            b += __shfl_down(b, off, 32);
        }
        if (i == 0) {
            float* o = out + (size_t)ray * 3;
            o[0] = r; o[1] = g; o[2] = b;
        }
    }
}

extern "C" void kernel_launch(void* const* d_in, const int* in_sizes, int n_in,
                              void* d_out, int out_size, void* d_ws, size_t ws_size,
                              hipStream_t stream) {
    const float4* dist4  = (const float4*)d_in[0];
    const float4* col4   = (const float4*)d_in[1];
    const float4* depth4 = (const float4*)d_in[2];
    float* out = (float*)d_out;

    const int n_rays = in_sizes[0] / N_PTS;                      // 65536
    const int blocks = n_rays / (WAVES_PER_BLOCK * RAYS_PER_WAVE); // 4096
    volsdf_render_kernel<<<blocks, 256, 0, stream>>>(dist4, depth4, col4, out);
}